// Round 1
// baseline (1050.801 us; speedup 1.0000x reference)
//
#include <hip/hip_runtime.h>
#include <stdint.h>

#define GAS __attribute__((address_space(1)))
#define LAS __attribute__((address_space(3)))

typedef int v4i __attribute__((ext_vector_type(4)));

constexpr int Mdim = 8192;    // B*S = 4*2048
constexpr int Ndim = 16384;   // D_OUT
constexpr int Kdim = 4096;    // D_IN
constexpr int BM = 128, BN = 128, BK = 64;
constexpr int KT = Kdim / BK; // 64

__device__ __forceinline__ int pack4i8(int a, int b, int c, int d) {
    return (a & 255) | ((b & 255) << 8) | ((c & 255) << 16) | ((d & 255) << 24);
}

__device__ __forceinline__ int qz(float v, float inv) {
    // round-to-nearest-even (matches jnp.round), clamp to [-128,127]
    return (int)fminf(fmaxf(rintf(v * inv), -128.0f), 127.0f);
}

// ---- pass 1: quantize x fp32 -> int8 (16 elems/thread) ----
__global__ void k_quant_x(const float* __restrict__ x, const float* __restrict__ asc,
                          int8_t* __restrict__ xq) {
    const int i = blockIdx.x * blockDim.x + threadIdx.x;
    const float inv = 1.0f / *asc;
    const float4* xv = (const float4*)x + (size_t)i * 4;
    float4 f0 = xv[0], f1 = xv[1], f2 = xv[2], f3 = xv[3];
    int4 o;
    o.x = pack4i8(qz(f0.x, inv), qz(f0.y, inv), qz(f0.z, inv), qz(f0.w, inv));
    o.y = pack4i8(qz(f1.x, inv), qz(f1.y, inv), qz(f1.z, inv), qz(f1.w, inv));
    o.z = pack4i8(qz(f2.x, inv), qz(f2.y, inv), qz(f2.z, inv), qz(f2.w, inv));
    o.w = pack4i8(qz(f3.x, inv), qz(f3.y, inv), qz(f3.z, inv), qz(f3.w, inv));
    ((int4*)xq)[i] = o;
}

// ---- pass 2: weight int32 (sign-extended int8) -> packed int8 ----
__global__ void k_conv_w(const int* __restrict__ w, int8_t* __restrict__ wq) {
    const int i = blockIdx.x * blockDim.x + threadIdx.x;
    const int4* wv = (const int4*)w + (size_t)i * 4;
    int4 a = wv[0], b = wv[1], c = wv[2], d = wv[3];
    int4 o;
    o.x = pack4i8(a.x, a.y, a.z, a.w);
    o.y = pack4i8(b.x, b.y, b.z, b.w);
    o.z = pack4i8(c.x, c.y, c.z, c.w);
    o.w = pack4i8(d.x, d.y, d.z, d.w);
    ((int4*)wq)[i] = o;
}

// ---- pass 3: 128x128x64 double-buffered i8 MFMA GEMM + dequant epilogue ----
// AQ: A already int8 in ws (global_load_lds).  BQ: B already int8 in ws.
template <bool AQ, bool BQ>
__global__ __launch_bounds__(256)
void k_gemm(const int8_t* __restrict__ Aq, const float* __restrict__ Xf,
            const int8_t* __restrict__ Bq, const int* __restrict__ W32,
            const float* __restrict__ wscale, const float* __restrict__ asc,
            const float* __restrict__ bias, float* __restrict__ out) {
    __shared__ __align__(16) int8_t As[2][BM * BK];  // 8 KB each
    __shared__ __align__(16) int8_t Bs[2][BN * BK];

    const int tid  = threadIdx.x;
    const int lane = tid & 63;
    const int wid  = tid >> 6;            // wave 0..3, 2x2 wave grid, 64x64 out each
    const int wm = wid >> 1, wn = wid & 1;
    const int lrow = lane & 15, kgrp = lane >> 4;

    // bijective XCD swizzle (grid = 8192, % 8 == 0), m-tile fastest so 64
    // consecutive blocks on one XCD share the same 512 KB weight panel in L2.
    const int cpx = gridDim.x >> 3;
    const int swz = ((int)blockIdx.x & 7) * cpx + ((int)blockIdx.x >> 3);
    const int mt = swz & (Mdim / BM - 1);
    const int nt = swz / (Mdim / BM);
    const int m0 = mt * BM, n0 = nt * BN;

    const float ascale = *asc;
    const float inv = 1.0f / ascale;

    v4i acc[4][4];
#pragma unroll
    for (int i = 0; i < 4; ++i)
#pragma unroll
        for (int j = 0; j < 4; ++j) acc[i][j] = (v4i){0, 0, 0, 0};

    auto stage = [&](int buf, int kt) {
        const int k0 = kt * BK;
        if constexpr (AQ) {
            // linear LDS dest: wave-uniform base + lane*16
            int8_t* lds = &As[buf][wid << 10];
            const int8_t* g = Aq + (size_t)(m0 + (tid >> 2)) * Kdim + k0 + ((tid & 3) << 4);
            __builtin_amdgcn_global_load_lds((const GAS void*)g, (LAS void*)lds, 16, 0, 0);
            __builtin_amdgcn_global_load_lds((const GAS void*)(g + (size_t)64 * Kdim),
                                             (LAS void*)(lds + 4096), 16, 0, 0);
        } else {
            // reg-staged on-the-fly quantization of fp32 x
            const int row = tid >> 1, cb = (tid & 1) << 5;
            const float4* src = (const float4*)(Xf + (size_t)(m0 + row) * Kdim + k0 + cb);
            int t[8];
#pragma unroll
            for (int j = 0; j < 8; ++j) {
                float4 f = src[j];
                t[j] = pack4i8(qz(f.x, inv), qz(f.y, inv), qz(f.z, inv), qz(f.w, inv));
            }
            int4* dst = (int4*)&As[buf][row * BK + cb];
            dst[0] = make_int4(t[0], t[1], t[2], t[3]);
            dst[1] = make_int4(t[4], t[5], t[6], t[7]);
        }
        if constexpr (BQ) {
            int8_t* lds = &Bs[buf][wid << 10];
            const int8_t* g = Bq + (size_t)(n0 + (tid >> 2)) * Kdim + k0 + ((tid & 3) << 4);
            __builtin_amdgcn_global_load_lds((const GAS void*)g, (LAS void*)lds, 16, 0, 0);
            __builtin_amdgcn_global_load_lds((const GAS void*)(g + (size_t)64 * Kdim),
                                             (LAS void*)(lds + 4096), 16, 0, 0);
        } else {
            // reg-staged pack of sign-extended int32 weights
            const int row = tid >> 1, cb = (tid & 1) << 5;
            const int4* src = (const int4*)(W32 + (size_t)(n0 + row) * Kdim + k0 + cb);
            int t[8];
#pragma unroll
            for (int j = 0; j < 8; ++j) {
                int4 vv = src[j];
                t[j] = pack4i8(vv.x, vv.y, vv.z, vv.w);
            }
            int4* dst = (int4*)&Bs[buf][row * BK + cb];
            dst[0] = make_int4(t[0], t[1], t[2], t[3]);
            dst[1] = make_int4(t[4], t[5], t[6], t[7]);
        }
    };

    stage(0, 0);
    for (int kt = 0; kt < KT; ++kt) {
        const int cur = kt & 1;
        __syncthreads();  // staging of buf `cur` complete; prev compute done
        if (kt + 1 < KT) stage(cur ^ 1, kt + 1);

        v4i a[4], b[4];
        const int koff = kgrp << 4;
#pragma unroll
        for (int i = 0; i < 4; ++i) {
            a[i] = *(const v4i*)&As[cur][(wm * 64 + i * 16 + lrow) * BK + koff];
            b[i] = *(const v4i*)&Bs[cur][(wn * 64 + i * 16 + lrow) * BK + koff];
        }
#pragma unroll
        for (int i = 0; i < 4; ++i)
#pragma unroll
            for (int j = 0; j < 4; ++j)
                acc[i][j] = __builtin_amdgcn_mfma_i32_16x16x64_i8(a[i], b[j], acc[i][j], 0, 0, 0);
    }

    // epilogue: y = i32 * (act_scale * wscale[n]) + bias[n], fp32 out
    // C/D layout (16x16): col = lane&15, row = (lane>>4)*4 + reg
#pragma unroll
    for (int j = 0; j < 4; ++j) {
        const int col = n0 + wn * 64 + j * 16 + lrow;
        const float sc = ascale * wscale[col];
        const float bb = bias[col];
#pragma unroll
        for (int i = 0; i < 4; ++i) {
            const int r0 = m0 + wm * 64 + i * 16 + (kgrp << 2);
            float* o = out + (size_t)r0 * Ndim + col;
#pragma unroll
            for (int r = 0; r < 4; ++r)
                o[(size_t)r * Ndim] = (float)acc[i][j][r] * sc + bb;
        }
    }
}

extern "C" void kernel_launch(void* const* d_in, const int* in_sizes, int n_in,
                              void* d_out, int out_size, void* d_ws, size_t ws_size,
                              hipStream_t stream) {
    const float* x      = (const float*)d_in[0];
    const int*   w32    = (const int*)d_in[1];   // int8 values sign-extended to int32
    const float* wscale = (const float*)d_in[2];
    const float* asc    = (const float*)d_in[3];
    const float* bias   = (const float*)d_in[4];
    float* out = (float*)d_out;

    const size_t nx = (size_t)Mdim * Kdim;  // 33,554,432 B for x_int8
    const size_t nw = (size_t)Ndim * Kdim;  // 67,108,864 B for w_int8
    int8_t* xq = (int8_t*)d_ws;
    int8_t* wq = xq + nx;

    const bool haveX = ws_size >= nx;
    const bool haveW = ws_size >= nx + nw;

    if (haveX) k_quant_x<<<(int)(nx / 16 / 256), 256, 0, stream>>>(x, asc, xq);
    if (haveW) k_conv_w<<<(int)(nw / 16 / 256), 256, 0, stream>>>(w32, wq);

    dim3 grid((Mdim / BM) * (Ndim / BN));  // 8192
    if (haveW)
        k_gemm<true, true><<<grid, 256, 0, stream>>>(xq, x, wq, w32, wscale, asc, bias, out);
    else if (haveX)
        k_gemm<true, false><<<grid, 256, 0, stream>>>(xq, x, wq, w32, wscale, asc, bias, out);
    else
        k_gemm<false, false><<<grid, 256, 0, stream>>>(xq, x, wq, w32, wscale, asc, bias, out);
}

// Round 2
// 882.476 us; speedup vs baseline: 1.1907x; 1.1907x over previous
//
#include <hip/hip_runtime.h>
#include <stdint.h>

#define GAS __attribute__((address_space(1)))
#define LAS __attribute__((address_space(3)))

typedef int v4i __attribute__((ext_vector_type(4)));

constexpr int Mdim = 8192;    // B*S = 4*2048
constexpr int Ndim = 16384;   // D_OUT
constexpr int Kdim = 4096;    // D_IN

__device__ __forceinline__ int pack4i8(int a, int b, int c, int d) {
    return (a & 255) | ((b & 255) << 8) | ((c & 255) << 16) | ((d & 255) << 24);
}

__device__ __forceinline__ int qz(float v, float inv) {
    return (int)fminf(fmaxf(rintf(v * inv), -128.0f), 127.0f);
}

// ---- pass 1: quantize x fp32 -> int8 (16 elems/thread) ----
__global__ void k_quant_x(const float* __restrict__ x, const float* __restrict__ asc,
                          int8_t* __restrict__ xq) {
    const int i = blockIdx.x * blockDim.x + threadIdx.x;
    const float inv = 1.0f / *asc;
    const float4* xv = (const float4*)x + (size_t)i * 4;
    float4 f0 = xv[0], f1 = xv[1], f2 = xv[2], f3 = xv[3];
    int4 o;
    o.x = pack4i8(qz(f0.x, inv), qz(f0.y, inv), qz(f0.z, inv), qz(f0.w, inv));
    o.y = pack4i8(qz(f1.x, inv), qz(f1.y, inv), qz(f1.z, inv), qz(f1.w, inv));
    o.z = pack4i8(qz(f2.x, inv), qz(f2.y, inv), qz(f2.z, inv), qz(f2.w, inv));
    o.w = pack4i8(qz(f3.x, inv), qz(f3.y, inv), qz(f3.z, inv), qz(f3.w, inv));
    ((int4*)xq)[i] = o;
}

// ---- pass 2: weight int32 (sign-extended int8) -> packed int8 ----
__global__ void k_conv_w(const int* __restrict__ w, int8_t* __restrict__ wq) {
    const int i = blockIdx.x * blockDim.x + threadIdx.x;
    const int4* wv = (const int4*)w + (size_t)i * 4;
    int4 a = wv[0], b = wv[1], c = wv[2], d = wv[3];
    int4 o;
    o.x = pack4i8(a.x, a.y, a.z, a.w);
    o.y = pack4i8(b.x, b.y, b.z, b.w);
    o.z = pack4i8(c.x, c.y, c.z, c.w);
    o.w = pack4i8(d.x, d.y, d.z, d.w);
    ((int4*)wq)[i] = o;
}

// ============================================================================
// pass 3 (main): 256x256 tile, 8 waves, 4-slot pipelined i8 GEMM.
//   - BK=64 bytes per K-tile, KT=64 K-tiles.
//   - LDS: 4 A-slots (16 KB) + 4 B-slots (16 KB) = 128 KiB, tile t in slot t&3.
//   - staging 2 tiles ahead via global_load_lds; counted vmcnt(6) (3 units in
//     flight), tail vmcnt(4)/vmcnt(0). Raw s_barrier only (no full drain).
//   - XOR swizzle (addr ^= ((row>>1)&3)<<4) applied on the GLOBAL SOURCE at
//     stage time and on the ds_read address (rule 21) -> conflict-free b128.
//   - 2 phases per K-tile (M-halves), 16 MFMA each, setprio around MFMA.
// ============================================================================
constexpr int KT2 = Kdim / 64;  // 64

__global__ __launch_bounds__(512, 2)
void k_gemm256(const int8_t* __restrict__ Aq, const int8_t* __restrict__ Bq,
               const float* __restrict__ wscale, const float* __restrict__ asc,
               const float* __restrict__ bias, float* __restrict__ out) {
    __shared__ __align__(16) int8_t lds[131072];
    const int tid = threadIdx.x, lane = tid & 63, w = tid >> 6;
    const int wm = w >> 2, wn = w & 3;              // 2M x 4N wave grid
    const int lrow = lane & 15, kgrp = lane >> 4;

    const int bid = blockIdx.x;                     // grid = 2048, %8 == 0
    const int swz = ((bid & 7) << 8) | (bid >> 3);  // bijective XCD swizzle
    const int mt = swz & 31, nt = swz >> 5;         // m fastest: share B panel
    const int m0 = mt << 8, n0 = nt << 8;

    int8_t* const A_lds = lds;
    int8_t* const B_lds = lds + 65536;

    // per-lane staging source geometry (inverse swizzle on global address)
    const int8_t* gA[2];
    const int8_t* gB[2];
#pragma unroll
    for (int j = 0; j < 2; ++j) {
        const int L  = (j << 13) | (w << 10) | (lane << 4);
        const int Ls = L ^ (((lane >> 3) & 3) << 4);   // involution
        const int srow = Ls >> 6, skb = Ls & 63;
        gA[j] = Aq + (size_t)(m0 + srow) * Kdim + skb;
        gB[j] = Bq + (size_t)(n0 + srow) * Kdim + skb;
    }

    auto stageA = [&](int tt) {
#pragma unroll
        for (int j = 0; j < 2; ++j) {
            int8_t* d = A_lds + ((tt & 3) << 14) + (j << 13) + (w << 10);
            __builtin_amdgcn_global_load_lds((const GAS void*)(gA[j] + tt * 64),
                                             (LAS void*)d, 16, 0, 0);
        }
    };
    auto stageB = [&](int tt) {
#pragma unroll
        for (int j = 0; j < 2; ++j) {
            int8_t* d = B_lds + ((tt & 3) << 14) + (j << 13) + (w << 10);
            __builtin_amdgcn_global_load_lds((const GAS void*)(gB[j] + tt * 64),
                                             (LAS void*)d, 16, 0, 0);
        }
    };

    const int kc = (kgrp ^ ((lrow >> 1) & 3)) << 4;  // swizzled k-byte offset
    const int arow0 = (wm << 7) + lrow;
    const int brow0 = (wn << 6) + lrow;

    v4i acc[8][4];
#pragma unroll
    for (int i = 0; i < 8; ++i)
#pragma unroll
        for (int j = 0; j < 4; ++j) acc[i][j] = (v4i){0, 0, 0, 0};

    // prologue: tiles 0,1 (slots 0,1); order u_A(0) u_B(0) u_A(1) u_B(1)
    stageA(0); stageB(0); stageA(1); stageB(1);

    v4i bfr[4];

    auto ktile = [&](int t, int vmw, bool iss) {
        const int8_t* As_ = A_lds + ((t & 3) << 14);
        const int8_t* Bs_ = B_lds + ((t & 3) << 14);
        // ---------- phase A ----------
        if (iss) stageA(t + 2);  // slot (t+2)&3: last read retired >=2 barriers ago
        if (vmw == 6)      asm volatile("s_waitcnt vmcnt(6)" ::: "memory");
        else if (vmw == 4) asm volatile("s_waitcnt vmcnt(4)" ::: "memory");
        else               asm volatile("s_waitcnt vmcnt(0)" ::: "memory");
        __builtin_amdgcn_s_barrier();          // tile t staged, all waves
        __builtin_amdgcn_sched_barrier(0);
        v4i a[4];
#pragma unroll
        for (int f = 0; f < 4; ++f)
            bfr[f] = *(const v4i*)(Bs_ + (brow0 + f * 16) * 64 + kc);
#pragma unroll
        for (int f = 0; f < 4; ++f)
            a[f] = *(const v4i*)(As_ + (arow0 + f * 16) * 64 + kc);
        __builtin_amdgcn_s_setprio(1);
#pragma unroll
        for (int fi = 0; fi < 4; ++fi)
#pragma unroll
            for (int fj = 0; fj < 4; ++fj)
                acc[fi][fj] = __builtin_amdgcn_mfma_i32_16x16x64_i8(a[fi], bfr[fj], acc[fi][fj], 0, 0, 0);
        __builtin_amdgcn_s_setprio(0);
        // ---------- phase B ----------
        if (iss) stageB(t + 2);
        __builtin_amdgcn_s_barrier();          // lockstep
        __builtin_amdgcn_sched_barrier(0);
#pragma unroll
        for (int f = 0; f < 4; ++f)
            a[f] = *(const v4i*)(As_ + (arow0 + 64 + f * 16) * 64 + kc);
        __builtin_amdgcn_s_setprio(1);
#pragma unroll
        for (int fi = 0; fi < 4; ++fi)
#pragma unroll
            for (int fj = 0; fj < 4; ++fj)
                acc[4 + fi][fj] = __builtin_amdgcn_mfma_i32_16x16x64_i8(a[fi], bfr[fj], acc[4 + fi][fj], 0, 0, 0);
        __builtin_amdgcn_s_setprio(0);
    };

    for (int t = 0; t < KT2 - 2; ++t) ktile(t, 6, true);
    ktile(KT2 - 2, 4, false);
    ktile(KT2 - 1, 0, false);

    // epilogue: y = i32 * (act_scale * wscale[n]) + bias[n]
    const float ascale = *asc;
#pragma unroll
    for (int fj = 0; fj < 4; ++fj) {
        const int col = n0 + (wn << 6) + fj * 16 + lrow;
        const float sc = ascale * wscale[col];
        const float bb = bias[col];
#pragma unroll
        for (int mi = 0; mi < 8; ++mi) {
            const int r0 = m0 + (wm << 7) + mi * 16 + (kgrp << 2);
            float* o = out + (size_t)r0 * Ndim + col;
#pragma unroll
            for (int q = 0; q < 4; ++q)
                o[(size_t)q * Ndim] = (float)acc[mi][fj][q] * sc + bb;
        }
    }
}

// ============================================================================
// fallback 128x128 kernel (only used if workspace is too small)
// ============================================================================
template <bool AQ, bool BQ>
__global__ __launch_bounds__(256)
void k_gemm(const int8_t* __restrict__ Aq, const float* __restrict__ Xf,
            const int8_t* __restrict__ Bq, const int* __restrict__ W32,
            const float* __restrict__ wscale, const float* __restrict__ asc,
            const float* __restrict__ bias, float* __restrict__ out) {
    constexpr int BM = 128, BN = 128, BK = 64;
    constexpr int KT = Kdim / BK;
    __shared__ __align__(16) int8_t As[2][BM * BK];
    __shared__ __align__(16) int8_t Bs[2][BN * BK];

    const int tid  = threadIdx.x;
    const int lane = tid & 63;
    const int wid  = tid >> 6;
    const int wm = wid >> 1, wn = wid & 1;
    const int lrow = lane & 15, kgrp = lane >> 4;

    const int cpx = gridDim.x >> 3;
    const int swz = ((int)blockIdx.x & 7) * cpx + ((int)blockIdx.x >> 3);
    const int mt = swz & (Mdim / BM - 1);
    const int nt = swz / (Mdim / BM);
    const int m0 = mt * BM, n0 = nt * BN;

    const float ascale = *asc;
    const float inv = 1.0f / ascale;

    v4i acc[4][4];
#pragma unroll
    for (int i = 0; i < 4; ++i)
#pragma unroll
        for (int j = 0; j < 4; ++j) acc[i][j] = (v4i){0, 0, 0, 0};

    auto stage = [&](int buf, int kt) {
        const int k0 = kt * BK;
        if constexpr (AQ) {
            int8_t* ldsp = &As[buf][wid << 10];
            const int8_t* g = Aq + (size_t)(m0 + (tid >> 2)) * Kdim + k0 + ((tid & 3) << 4);
            __builtin_amdgcn_global_load_lds((const GAS void*)g, (LAS void*)ldsp, 16, 0, 0);
            __builtin_amdgcn_global_load_lds((const GAS void*)(g + (size_t)64 * Kdim),
                                             (LAS void*)(ldsp + 4096), 16, 0, 0);
        } else {
            const int row = tid >> 1, cb = (tid & 1) << 5;
            const float4* src = (const float4*)(Xf + (size_t)(m0 + row) * Kdim + k0 + cb);
            int t[8];
#pragma unroll
            for (int j = 0; j < 8; ++j) {
                float4 f = src[j];
                t[j] = pack4i8(qz(f.x, inv), qz(f.y, inv), qz(f.z, inv), qz(f.w, inv));
            }
            int4* dst = (int4*)&As[buf][row * BK + cb];
            dst[0] = make_int4(t[0], t[1], t[2], t[3]);
            dst[1] = make_int4(t[4], t[5], t[6], t[7]);
        }
        if constexpr (BQ) {
            int8_t* ldsp = &Bs[buf][wid << 10];
            const int8_t* g = Bq + (size_t)(n0 + (tid >> 2)) * Kdim + k0 + ((tid & 3) << 4);
            __builtin_amdgcn_global_load_lds((const GAS void*)g, (LAS void*)ldsp, 16, 0, 0);
            __builtin_amdgcn_global_load_lds((const GAS void*)(g + (size_t)64 * Kdim),
                                             (LAS void*)(ldsp + 4096), 16, 0, 0);
        } else {
            const int row = tid >> 1, cb = (tid & 1) << 5;
            const int4* src = (const int4*)(W32 + (size_t)(n0 + row) * Kdim + k0 + cb);
            int t[8];
#pragma unroll
            for (int j = 0; j < 8; ++j) {
                int4 vv = src[j];
                t[j] = pack4i8(vv.x, vv.y, vv.z, vv.w);
            }
            int4* dst = (int4*)&Bs[buf][row * BK + cb];
            dst[0] = make_int4(t[0], t[1], t[2], t[3]);
            dst[1] = make_int4(t[4], t[5], t[6], t[7]);
        }
    };

    stage(0, 0);
    for (int kt = 0; kt < KT; ++kt) {
        const int cur = kt & 1;
        __syncthreads();
        if (kt + 1 < KT) stage(cur ^ 1, kt + 1);

        v4i a[4], b[4];
        const int koff = kgrp << 4;
#pragma unroll
        for (int i = 0; i < 4; ++i) {
            a[i] = *(const v4i*)&As[cur][(wm * 64 + i * 16 + lrow) * BK + koff];
            b[i] = *(const v4i*)&Bs[cur][(wn * 64 + i * 16 + lrow) * BK + koff];
        }
#pragma unroll
        for (int i = 0; i < 4; ++i)
#pragma unroll
            for (int j = 0; j < 4; ++j)
                acc[i][j] = __builtin_amdgcn_mfma_i32_16x16x64_i8(a[i], b[j], acc[i][j], 0, 0, 0);
    }

#pragma unroll
    for (int j = 0; j < 4; ++j) {
        const int col = n0 + wn * 64 + j * 16 + lrow;
        const float sc = ascale * wscale[col];
        const float bb = bias[col];
#pragma unroll
        for (int i = 0; i < 4; ++i) {
            const int r0 = m0 + wm * 64 + i * 16 + (kgrp << 2);
            float* o = out + (size_t)r0 * Ndim + col;
#pragma unroll
            for (int r = 0; r < 4; ++r)
                o[(size_t)r * Ndim] = (float)acc[i][j][r] * sc + bb;
        }
    }
}

extern "C" void kernel_launch(void* const* d_in, const int* in_sizes, int n_in,
                              void* d_out, int out_size, void* d_ws, size_t ws_size,
                              hipStream_t stream) {
    const float* x      = (const float*)d_in[0];
    const int*   w32    = (const int*)d_in[1];   // int8 values sign-extended to int32
    const float* wscale = (const float*)d_in[2];
    const float* asc    = (const float*)d_in[3];
    const float* bias   = (const float*)d_in[4];
    float* out = (float*)d_out;

    const size_t nx = (size_t)Mdim * Kdim;  // 33,554,432 B for x_int8
    const size_t nw = (size_t)Ndim * Kdim;  // 67,108,864 B for w_int8
    int8_t* xq = (int8_t*)d_ws;
    int8_t* wq = xq + nx;

    const bool haveX = ws_size >= nx;
    const bool haveW = ws_size >= nx + nw;

    if (haveX) k_quant_x<<<(int)(nx / 16 / 256), 256, 0, stream>>>(x, asc, xq);
    if (haveW) k_conv_w<<<(int)(nw / 16 / 256), 256, 0, stream>>>(w32, wq);

    if (haveW) {
        dim3 grid((Mdim / 256) * (Ndim / 256));  // 2048
        k_gemm256<<<grid, 512, 0, stream>>>(xq, wq, wscale, asc, bias, out);
    } else if (haveX) {
        dim3 grid((Mdim / 128) * (Ndim / 128));  // 8192
        k_gemm<true, false><<<grid, 256, 0, stream>>>(xq, x, wq, w32, wscale, asc, bias, out);
    } else {
        dim3 grid((Mdim / 128) * (Ndim / 128));
        k_gemm<false, false><<<grid, 256, 0, stream>>>(xq, x, wq, w32, wscale, asc, bias, out);
    }
}

// Round 3
// 823.926 us; speedup vs baseline: 1.2754x; 1.0711x over previous
//
#include <hip/hip_runtime.h>
#include <stdint.h>

#define GAS __attribute__((address_space(1)))
#define LAS __attribute__((address_space(3)))

typedef int v4i __attribute__((ext_vector_type(4)));

constexpr int Mdim = 8192;    // B*S = 4*2048
constexpr int Ndim = 16384;   // D_OUT
constexpr int Kdim = 4096;    // D_IN

__device__ __forceinline__ int pack4i8(int a, int b, int c, int d) {
    return (a & 255) | ((b & 255) << 8) | ((c & 255) << 16) | ((d & 255) << 24);
}

__device__ __forceinline__ int qz(float v, float inv) {
    return (int)fminf(fmaxf(rintf(v * inv), -128.0f), 127.0f);
}

// ---- pass 1: quantize x fp32 -> int8 (16 elems/thread) ----
__global__ void k_quant_x(const float* __restrict__ x, const float* __restrict__ asc,
                          int8_t* __restrict__ xq) {
    const int i = blockIdx.x * blockDim.x + threadIdx.x;
    const float inv = 1.0f / *asc;
    const float4* xv = (const float4*)x + (size_t)i * 4;
    float4 f0 = xv[0], f1 = xv[1], f2 = xv[2], f3 = xv[3];
    int4 o;
    o.x = pack4i8(qz(f0.x, inv), qz(f0.y, inv), qz(f0.z, inv), qz(f0.w, inv));
    o.y = pack4i8(qz(f1.x, inv), qz(f1.y, inv), qz(f1.z, inv), qz(f1.w, inv));
    o.z = pack4i8(qz(f2.x, inv), qz(f2.y, inv), qz(f2.z, inv), qz(f2.w, inv));
    o.w = pack4i8(qz(f3.x, inv), qz(f3.y, inv), qz(f3.z, inv), qz(f3.w, inv));
    ((int4*)xq)[i] = o;
}

// ---- pass 2: weight int32 (sign-extended int8) -> packed int8 ----
__global__ void k_conv_w(const int* __restrict__ w, int8_t* __restrict__ wq) {
    const int i = blockIdx.x * blockDim.x + threadIdx.x;
    const int4* wv = (const int4*)w + (size_t)i * 4;
    int4 a = wv[0], b = wv[1], c = wv[2], d = wv[3];
    int4 o;
    o.x = pack4i8(a.x, a.y, a.z, a.w);
    o.y = pack4i8(b.x, b.y, b.z, b.w);
    o.z = pack4i8(c.x, c.y, c.z, c.w);
    o.w = pack4i8(d.x, d.y, d.z, d.w);
    ((int4*)wq)[i] = o;
}

// ============================================================================
// pass 3 (main): 256x256 tile, 8 waves, 4-slot pipelined i8 GEMM,
// m201-template phase schedule:
//   per K-step (BK=64B), 2 phases; each phase:
//     {ds_read subtile ; stage 2x8KB units (slot s+2) ; [vmcnt] ; s_barrier ;
//      lgkmcnt(0)+sched_barrier ; setprio(1) 16 MFMA setprio(0) ; s_barrier}
//   vmcnt(4) once per step (phase B) -> validates slot s+1, never drains
//   the in-flight step-s loads. Tail: vmcnt(0) at s==NSTEP-2 only.
//   LDS: 4 slots x (16KB A + 16KB B) = 128 KiB. Read swizzle
//   kc = (kgrp ^ ((lrow>>1)&3))<<4 with matching inverse-swizzled global
//   staging source (both verified round 2: SQ_LDS_BANK_CONFLICT == 0).
// ============================================================================
constexpr int NSTEP = Kdim / 64;  // 64

__global__ __launch_bounds__(512, 2)
void k_gemm256(const int8_t* __restrict__ Aq, const int8_t* __restrict__ Bq,
               const float* __restrict__ wscale, const float* __restrict__ asc,
               const float* __restrict__ bias, float* __restrict__ out) {
    __shared__ __align__(16) int8_t lds[131072];
    const int tid = threadIdx.x, lane = tid & 63, w = tid >> 6;
    const int wm = w >> 2, wn = w & 3;              // 2M x 4N wave grid
    const int lrow = lane & 15, kgrp = lane >> 4;

    const int bid = blockIdx.x;                     // grid = 2048, %8 == 0
    const int swz = ((bid & 7) << 8) | (bid >> 3);  // bijective XCD swizzle
    const int mt = swz & 31, nt = swz >> 5;         // m fastest: share B panel
    const int m0 = mt << 8, n0 = nt << 8;

    int8_t* const A_lds = lds;
    int8_t* const B_lds = lds + 65536;

    // staging geometry: unit = 8 KB = 128 rows x 64 B; 1 gload/thread/unit.
    // LDS dest linear: row_in_unit = w*16 + (lane>>2), phys slot = lane&3.
    // source col pre-swizzled by the read involution slot^((row>>1)&3):
    const int srow = (w << 4) + (lane >> 2);
    const int scol = (((lane & 3) ^ ((lane >> 3) & 3)) << 4);
    const int8_t* gAu0 = Aq + (size_t)(m0 + srow) * Kdim + scol;
    const int8_t* gAu1 = Aq + (size_t)(m0 + 128 + srow) * Kdim + scol;
    const int8_t* gBu0 = Bq + (size_t)(n0 + srow) * Kdim + scol;
    const int8_t* gBu1 = Bq + (size_t)(n0 + 128 + srow) * Kdim + scol;
    const int dstoff = w << 10;  // wave-uniform base; HW adds lane*16

    auto stageB2 = [&](int s2) {
        int8_t* base = B_lds + ((s2 & 3) << 14) + dstoff;
        __builtin_amdgcn_global_load_lds((const GAS void*)(gBu0 + s2 * 64), (LAS void*)base, 16, 0, 0);
        __builtin_amdgcn_global_load_lds((const GAS void*)(gBu1 + s2 * 64), (LAS void*)(base + 8192), 16, 0, 0);
    };
    auto stageA2 = [&](int s2) {
        int8_t* base = A_lds + ((s2 & 3) << 14) + dstoff;
        __builtin_amdgcn_global_load_lds((const GAS void*)(gAu0 + s2 * 64), (LAS void*)base, 16, 0, 0);
        __builtin_amdgcn_global_load_lds((const GAS void*)(gAu1 + s2 * 64), (LAS void*)(base + 8192), 16, 0, 0);
    };

    // read-side addressing (verified conflict-free, round 2)
    const int kc = (kgrp ^ ((lrow >> 1) & 3)) << 4;   // swizzled k-byte
    const int arowb = (((wm << 7) + lrow) << 6) + kc; // base row byte offset
    const int browb = (((wn << 6) + lrow) << 6) + kc;

    v4i acc[8][4];
#pragma unroll
    for (int i = 0; i < 8; ++i)
#pragma unroll
        for (int j = 0; j < 4; ++j) acc[i][j] = (v4i){0, 0, 0, 0};

    // prologue: slots 0,1 (8 loads); validate slot 0
    stageB2(0); stageA2(0); stageB2(1); stageA2(1);
    asm volatile("s_waitcnt vmcnt(4)" ::: "memory");
    __builtin_amdgcn_s_barrier();

    v4i a[4], b[4];
    for (int s = 0; s < NSTEP; ++s) {
        const int8_t* As_ = A_lds + ((s & 3) << 14);
        const int8_t* Bs_ = B_lds + ((s & 3) << 14);
        const bool st = s < NSTEP - 2;
        // ================= phase A (mi 0-3) =================
#pragma unroll
        for (int f = 0; f < 4; ++f)
            b[f] = *(const v4i*)(Bs_ + browb + f * 1024);
#pragma unroll
        for (int f = 0; f < 4; ++f)
            a[f] = *(const v4i*)(As_ + arowb + f * 1024);
        if (st) stageB2(s + 2);
        __builtin_amdgcn_s_barrier();
        asm volatile("s_waitcnt lgkmcnt(0)" ::: "memory");
        __builtin_amdgcn_sched_barrier(0);
        __builtin_amdgcn_s_setprio(1);
#pragma unroll
        for (int fi = 0; fi < 4; ++fi)
#pragma unroll
            for (int fj = 0; fj < 4; ++fj)
                acc[fi][fj] = __builtin_amdgcn_mfma_i32_16x16x64_i8(a[fi], b[fj], acc[fi][fj], 0, 0, 0);
        __builtin_amdgcn_s_setprio(0);
        __builtin_amdgcn_s_barrier();
        // ================= phase B (mi 4-7) =================
#pragma unroll
        for (int f = 0; f < 4; ++f)
            a[f] = *(const v4i*)(As_ + arowb + 4096 + f * 1024);
        if (st) stageA2(s + 2);
        if (st)                    asm volatile("s_waitcnt vmcnt(4)" ::: "memory");
        else if (s == NSTEP - 2)   asm volatile("s_waitcnt vmcnt(0)" ::: "memory");
        __builtin_amdgcn_s_barrier();
        asm volatile("s_waitcnt lgkmcnt(0)" ::: "memory");
        __builtin_amdgcn_sched_barrier(0);
        __builtin_amdgcn_s_setprio(1);
#pragma unroll
        for (int fi = 0; fi < 4; ++fi)
#pragma unroll
            for (int fj = 0; fj < 4; ++fj)
                acc[4 + fi][fj] = __builtin_amdgcn_mfma_i32_16x16x64_i8(a[fi], b[fj], acc[4 + fi][fj], 0, 0, 0);
        __builtin_amdgcn_s_setprio(0);
        __builtin_amdgcn_s_barrier();
    }

    // epilogue: y = i32 * (act_scale * wscale[n]) + bias[n]
    const float ascale = *asc;
#pragma unroll
    for (int fj = 0; fj < 4; ++fj) {
        const int col = n0 + (wn << 6) + fj * 16 + lrow;
        const float sc = ascale * wscale[col];
        const float bb = bias[col];
#pragma unroll
        for (int mi = 0; mi < 8; ++mi) {
            const int r0 = m0 + (wm << 7) + mi * 16 + (kgrp << 2);
            float* o = out + (size_t)r0 * Ndim + col;
#pragma unroll
            for (int q = 0; q < 4; ++q)
                o[(size_t)q * Ndim] = (float)acc[mi][fj][q] * sc + bb;
        }
    }
}

// ============================================================================
// fallback 128x128 kernel (only used if workspace is too small)
// ============================================================================
template <bool AQ, bool BQ>
__global__ __launch_bounds__(256)
void k_gemm(const int8_t* __restrict__ Aq, const float* __restrict__ Xf,
            const int8_t* __restrict__ Bq, const int* __restrict__ W32,
            const float* __restrict__ wscale, const float* __restrict__ asc,
            const float* __restrict__ bias, float* __restrict__ out) {
    constexpr int BM = 128, BN = 128, BK = 64;
    constexpr int KT = Kdim / BK;
    __shared__ __align__(16) int8_t As[2][BM * BK];
    __shared__ __align__(16) int8_t Bs[2][BN * BK];

    const int tid  = threadIdx.x;
    const int lane = tid & 63;
    const int wid  = tid >> 6;
    const int wm = wid >> 1, wn = wid & 1;
    const int lrow = lane & 15, kgrp = lane >> 4;

    const int cpx = gridDim.x >> 3;
    const int swz = ((int)blockIdx.x & 7) * cpx + ((int)blockIdx.x >> 3);
    const int mt = swz & (Mdim / BM - 1);
    const int nt = swz / (Mdim / BM);
    const int m0 = mt * BM, n0 = nt * BN;

    const float ascale = *asc;
    const float inv = 1.0f / ascale;

    v4i acc[4][4];
#pragma unroll
    for (int i = 0; i < 4; ++i)
#pragma unroll
        for (int j = 0; j < 4; ++j) acc[i][j] = (v4i){0, 0, 0, 0};

    auto stage = [&](int buf, int kt) {
        const int k0 = kt * BK;
        if constexpr (AQ) {
            int8_t* ldsp = &As[buf][wid << 10];
            const int8_t* g = Aq + (size_t)(m0 + (tid >> 2)) * Kdim + k0 + ((tid & 3) << 4);
            __builtin_amdgcn_global_load_lds((const GAS void*)g, (LAS void*)ldsp, 16, 0, 0);
            __builtin_amdgcn_global_load_lds((const GAS void*)(g + (size_t)64 * Kdim),
                                             (LAS void*)(ldsp + 4096), 16, 0, 0);
        } else {
            const int row = tid >> 1, cb = (tid & 1) << 5;
            const float4* src = (const float4*)(Xf + (size_t)(m0 + row) * Kdim + k0 + cb);
            int t[8];
#pragma unroll
            for (int j = 0; j < 8; ++j) {
                float4 f = src[j];
                t[j] = pack4i8(qz(f.x, inv), qz(f.y, inv), qz(f.z, inv), qz(f.w, inv));
            }
            int4* dst = (int4*)&As[buf][row * BK + cb];
            dst[0] = make_int4(t[0], t[1], t[2], t[3]);
            dst[1] = make_int4(t[4], t[5], t[6], t[7]);
        }
        if constexpr (BQ) {
            int8_t* ldsp = &Bs[buf][wid << 10];
            const int8_t* g = Bq + (size_t)(n0 + (tid >> 2)) * Kdim + k0 + ((tid & 3) << 4);
            __builtin_amdgcn_global_load_lds((const GAS void*)g, (LAS void*)ldsp, 16, 0, 0);
            __builtin_amdgcn_global_load_lds((const GAS void*)(g + (size_t)64 * Kdim),
                                             (LAS void*)(ldsp + 4096), 16, 0, 0);
        } else {
            const int row = tid >> 1, cb = (tid & 1) << 5;
            const int4* src = (const int4*)(W32 + (size_t)(n0 + row) * Kdim + k0 + cb);
            int t[8];
#pragma unroll
            for (int j = 0; j < 8; ++j) {
                int4 vv = src[j];
                t[j] = pack4i8(vv.x, vv.y, vv.z, vv.w);
            }
            int4* dst = (int4*)&Bs[buf][row * BK + cb];
            dst[0] = make_int4(t[0], t[1], t[2], t[3]);
            dst[1] = make_int4(t[4], t[5], t[6], t[7]);
        }
    };

    stage(0, 0);
    for (int kt = 0; kt < KT; ++kt) {
        const int cur = kt & 1;
        __syncthreads();
        if (kt + 1 < KT) stage(cur ^ 1, kt + 1);

        v4i a[4], b[4];
        const int koff = kgrp << 4;
#pragma unroll
        for (int i = 0; i < 4; ++i) {
            a[i] = *(const v4i*)&As[cur][(wm * 64 + i * 16 + lrow) * BK + koff];
            b[i] = *(const v4i*)&Bs[cur][(wn * 64 + i * 16 + lrow) * BK + koff];
        }
#pragma unroll
        for (int i = 0; i < 4; ++i)
#pragma unroll
            for (int j = 0; j < 4; ++j)
                acc[i][j] = __builtin_amdgcn_mfma_i32_16x16x64_i8(a[i], b[j], acc[i][j], 0, 0, 0);
    }

#pragma unroll
    for (int j = 0; j < 4; ++j) {
        const int col = n0 + wn * 64 + j * 16 + lrow;
        const float sc = ascale * wscale[col];
        const float bb = bias[col];
#pragma unroll
        for (int i = 0; i < 4; ++i) {
            const int r0 = m0 + wm * 64 + i * 16 + (kgrp << 2);
            float* o = out + (size_t)r0 * Ndim + col;
#pragma unroll
            for (int r = 0; r < 4; ++r)
                o[(size_t)r * Ndim] = (float)acc[i][j][r] * sc + bb;
        }
    }
}

extern "C" void kernel_launch(void* const* d_in, const int* in_sizes, int n_in,
                              void* d_out, int out_size, void* d_ws, size_t ws_size,
                              hipStream_t stream) {
    const float* x      = (const float*)d_in[0];
    const int*   w32    = (const int*)d_in[1];   // int8 values sign-extended to int32
    const float* wscale = (const float*)d_in[2];
    const float* asc    = (const float*)d_in[3];
    const float* bias   = (const float*)d_in[4];
    float* out = (float*)d_out;

    const size_t nx = (size_t)Mdim * Kdim;  // 33,554,432 B for x_int8
    const size_t nw = (size_t)Ndim * Kdim;  // 67,108,864 B for w_int8
    int8_t* xq = (int8_t*)d_ws;
    int8_t* wq = xq + nx;

    const bool haveX = ws_size >= nx;
    const bool haveW = ws_size >= nx + nw;

    if (haveX) k_quant_x<<<(int)(nx / 16 / 256), 256, 0, stream>>>(x, asc, xq);
    if (haveW) k_conv_w<<<(int)(nw / 16 / 256), 256, 0, stream>>>(w32, wq);

    if (haveW) {
        dim3 grid((Mdim / 256) * (Ndim / 256));  // 2048
        k_gemm256<<<grid, 512, 0, stream>>>(xq, wq, wscale, asc, bias, out);
    } else if (haveX) {
        dim3 grid((Mdim / 128) * (Ndim / 128));  // 8192
        k_gemm<true, false><<<grid, 256, 0, stream>>>(xq, x, wq, w32, wscale, asc, bias, out);
    } else {
        dim3 grid((Mdim / 128) * (Ndim / 128));
        k_gemm<false, false><<<grid, 256, 0, stream>>>(xq, x, wq, w32, wscale, asc, bias, out);
    }
}